// Round 9
// baseline (370.470 us; speedup 1.0000x reference)
//
#include <hip/hip_runtime.h>
#include <hip/hip_bf16.h>
#include <hip/hip_fp16.h>

#define NDIM_IN 128
#define HID 64

#define BINW 128          // dst values per bin
#define NB   782          // ceil(100000/128)
#define NC   256          // phase-1 blocks == scan1 block size (alignment!)
#define CAP  3072         // LDS edge buffer per bin (mean 2046, +22 sigma)

// ---------------------------------------------------------------------------
// Phase 1a: per-block LDS histogram over bins, written transposed:
// histT[bin*NC + block]. No global atomics, no memset needed.
// ---------------------------------------------------------------------------
__global__ __launch_bounds__(256) void hist_k(const int* __restrict__ dst,
                                              int* __restrict__ histT, int E) {
  __shared__ int h[NB];
  for (int i = threadIdx.x; i < NB; i += 256) h[i] = 0;
  __syncthreads();
  int E4 = E >> 2;
  int chunk = (E4 + NC - 1) / NC;
  int beg = blockIdx.x * chunk;
  int end = min(E4, beg + chunk);
  const int4* __restrict__ d4 = (const int4*)dst;
  for (int i = beg + (int)threadIdx.x; i < end; i += 256) {
    int4 d = d4[i];
    atomicAdd(&h[d.x >> 7], 1);
    atomicAdd(&h[d.y >> 7], 1);
    atomicAdd(&h[d.z >> 7], 1);
    atomicAdd(&h[d.w >> 7], 1);
  }
  __syncthreads();
  for (int i = threadIdx.x; i < NB; i += 256)
    histT[i * NC + blockIdx.x] = h[i];
}

// ---------------------------------------------------------------------------
// scan1: per-256-block exclusive scan in-place + block sums. Because the
// scan block size == NC, scan-block b covers exactly bin b -> after scan2,
// bsum[bin] IS the global bin base (no scan3 pass needed).
// ---------------------------------------------------------------------------
__global__ __launch_bounds__(256) void scan1(int* __restrict__ g,
                                             int* __restrict__ bs, int len) {
  __shared__ int s[256];
  int t = threadIdx.x;
  int i = blockIdx.x * 256 + t;
  int v = (i < len) ? g[i] : 0;
  s[t] = v;
  __syncthreads();
  for (int off = 1; off < 256; off <<= 1) {
    int x = (t >= off) ? s[t - off] : 0;
    __syncthreads();
    s[t] += x;
    __syncthreads();
  }
  if (i < len) g[i] = s[t] - v;          // exclusive within block
  if (t == 255) bs[blockIdx.x] = s[255];
}

__global__ __launch_bounds__(1024) void scan2(int* __restrict__ bs, int nb) {
  __shared__ int s[1024];
  int t = threadIdx.x;
  int v = (t < nb) ? bs[t] : 0;
  s[t] = v;
  __syncthreads();
  for (int off = 1; off < 1024; off <<= 1) {
    int x = (t >= off) ? s[t - off] : 0;
    __syncthreads();
    s[t] += x;
    __syncthreads();
  }
  if (t < nb) bs[t] = s[t] - v;          // exclusive bin bases
}

// ---------------------------------------------------------------------------
// Phase 1c: scatter packed (src<<7 | dst&127) into tmp, grouped by bin.
// LDS cursor seed = within-bin partial (S) + global bin base (bsum).
// ---------------------------------------------------------------------------
__global__ __launch_bounds__(256) void scatter_k(const int* __restrict__ src,
                                                 const int* __restrict__ dst,
                                                 const int* __restrict__ S,
                                                 const int* __restrict__ bsum,
                                                 int* __restrict__ tmp, int E) {
  __shared__ int cur[NB];
  for (int i = threadIdx.x; i < NB; i += 256)
    cur[i] = S[i * NC + blockIdx.x] + bsum[i];
  __syncthreads();
  int E4 = E >> 2;
  int chunk = (E4 + NC - 1) / NC;
  int beg = blockIdx.x * chunk;
  int end = min(E4, beg + chunk);
  const int4* __restrict__ d4 = (const int4*)dst;
  const int4* __restrict__ s4 = (const int4*)src;
  for (int i = beg + (int)threadIdx.x; i < end; i += 256) {
    int4 d = d4[i];
    int4 sv = s4[i];
    int p0 = atomicAdd(&cur[d.x >> 7], 1); tmp[p0] = (sv.x << 7) | (d.x & 127);
    int p1 = atomicAdd(&cur[d.y >> 7], 1); tmp[p1] = (sv.y << 7) | (d.y & 127);
    int p2 = atomicAdd(&cur[d.z >> 7], 1); tmp[p2] = (sv.z << 7) | (d.z & 127);
    int p3 = atomicAdd(&cur[d.w >> 7], 1); tmp[p3] = (sv.w << 7) | (d.w & 127);
  }
}

// ---------------------------------------------------------------------------
// Phase 2: one block per bin. Exact in-LDS counting sort by dst within the
// bin; emits col (coalesced), rp, and dinv. All atomics are LDS.
// ---------------------------------------------------------------------------
__global__ __launch_bounds__(256) void binsort_k(const int* __restrict__ tmp,
                                                 const int* __restrict__ bsum,
                                                 int* __restrict__ col,
                                                 int* __restrict__ rp,
                                                 float* __restrict__ dinv,
                                                 int n, int E) {
  int bin = blockIdx.x;
  int base = bsum[bin];
  int end = (bin == NB - 1) ? E : bsum[bin + 1];
  int m = end - base;
  __shared__ int cnt[BINW];
  __shared__ int offs[BINW];
  __shared__ int cur[BINW];
  __shared__ int buf[CAP];
  int t = threadIdx.x;
  if (t < BINW) cnt[t] = 0;
  __syncthreads();
  for (int i = t; i < m; i += 256) {
    int p = tmp[base + i];
    atomicAdd(&cnt[p & (BINW - 1)], 1);
  }
  __syncthreads();
  if (t < BINW) offs[t] = cnt[t];
  __syncthreads();
  for (int off = 1; off < BINW; off <<= 1) {
    int x = (t < BINW && t >= off) ? offs[t - off] : 0;
    __syncthreads();
    if (t < BINW) offs[t] += x;
    __syncthreads();
  }
  if (t < BINW) {
    int ex = offs[t] - cnt[t];             // exclusive
    cur[t] = ex;
    int v = bin * BINW + t;
    if (v < n) {
      rp[v] = base + ex;
      dinv[v] = rsqrtf((float)cnt[t] + 1.0f);  // +1 = self loop
    }
  }
  if (bin == NB - 1 && t == 0) rp[n] = E;
  __syncthreads();
  for (int i = t; i < m; i += 256) {
    int p = tmp[base + i];
    int r = atomicAdd(&cur[p & (BINW - 1)], 1);
    if (r < CAP) buf[r] = p >> 7;          // unpacked src
  }
  __syncthreads();
  int mm = min(m, CAP);
  for (int i = t; i < mm; i += 256) col[base + i] = buf[i];
}

// ---------------------------------------------------------------------------
// Dense transform T' = (X @ W) * dinv[row], output fp16.
// Block = 256 threads = 64 nodes x 4 out-groups (og wave-uniform; 16 outs).
// X staged in LDS (stride K+1); W via wave-uniform addresses -> s_load.
// ---------------------------------------------------------------------------
template <int K>
__global__ __launch_bounds__(256) void gemm_xw(const float* __restrict__ X,
                                               const float* __restrict__ W,
                                               const float* __restrict__ dinv,
                                               __half* __restrict__ T, int n) {
  constexpr int STR = K + 1;
  constexpr int RF4 = K / 4;  // float4 per row
  __shared__ float Xs[64 * STR];
  int t = threadIdx.x;
  int node0 = blockIdx.x * 64;
  for (int i = t; i < 64 * RF4; i += 256) {
    int r = i / RF4, c = i % RF4;
    int node = node0 + r;
    float4 v = make_float4(0.f, 0.f, 0.f, 0.f);
    if (node < n) v = *(const float4*)(X + (size_t)node * K + c * 4);
    float* p = &Xs[r * STR + c * 4];
    p[0] = v.x; p[1] = v.y; p[2] = v.z; p[3] = v.w;
  }
  __syncthreads();
  int lane = t & 63;
  int og = __builtin_amdgcn_readfirstlane(t >> 6);  // wave-uniform out-group
  int node = node0 + lane;
  const float* __restrict__ Wg = W + og * 16;       // uniform -> s_load
  const float* __restrict__ xrow = &Xs[lane * STR];
  float4 a0 = make_float4(0.f, 0.f, 0.f, 0.f);
  float4 a1 = make_float4(0.f, 0.f, 0.f, 0.f);
  float4 a2 = make_float4(0.f, 0.f, 0.f, 0.f);
  float4 a3 = make_float4(0.f, 0.f, 0.f, 0.f);
#pragma unroll 4
  for (int k = 0; k < K; k++) {
    float xk = xrow[k];
    const float* __restrict__ wk = Wg + k * 64;
    a0.x += xk * wk[0];  a0.y += xk * wk[1];  a0.z += xk * wk[2];  a0.w += xk * wk[3];
    a1.x += xk * wk[4];  a1.y += xk * wk[5];  a1.z += xk * wk[6];  a1.w += xk * wk[7];
    a2.x += xk * wk[8];  a2.y += xk * wk[9];  a2.z += xk * wk[10]; a2.w += xk * wk[11];
    a3.x += xk * wk[12]; a3.y += xk * wk[13]; a3.z += xk * wk[14]; a3.w += xk * wk[15];
  }
  if (node >= n) return;
  float di = dinv[node];
  __half2 h0 = __floats2half2_rn(a0.x * di, a0.y * di);
  __half2 h1 = __floats2half2_rn(a0.z * di, a0.w * di);
  __half2 h2 = __floats2half2_rn(a1.x * di, a1.y * di);
  __half2 h3 = __floats2half2_rn(a1.z * di, a1.w * di);
  __half2 h4 = __floats2half2_rn(a2.x * di, a2.y * di);
  __half2 h5 = __floats2half2_rn(a2.z * di, a2.w * di);
  __half2 h6 = __floats2half2_rn(a3.x * di, a3.y * di);
  __half2 h7 = __floats2half2_rn(a3.z * di, a3.w * di);
  uint4* __restrict__ o = (uint4*)(T + (size_t)node * 64 + og * 16);
  uint4 p0, p1;
  p0.x = *(unsigned int*)&h0; p0.y = *(unsigned int*)&h1;
  p0.z = *(unsigned int*)&h2; p0.w = *(unsigned int*)&h3;
  p1.x = *(unsigned int*)&h4; p1.y = *(unsigned int*)&h5;
  p1.z = *(unsigned int*)&h6; p1.w = *(unsigned int*)&h7;
  o[0] = p0;
  o[1] = p1;
}

// ---------------------------------------------------------------------------
// SpMM gather: wave-per-node, 4 groups x 16 lanes, uint2 (4 fp16 feats).
// ONE pass of 8 guarded chains covers 32 edges -> since deg~Poisson(16),
// 99.99% of nodes need a single col-round + row-round with 8 gathers in
// flight. Guards are branchless: clamped index + {0,1} mask folded into FMA
// (products exact) so all 8 chains' loads issue in parallel.
// ---------------------------------------------------------------------------
__global__ __launch_bounds__(256) void spmm_relu(const int* __restrict__ rp,
                                                 const int* __restrict__ col,
                                                 const __half* __restrict__ T,
                                                 const float* __restrict__ dinv,
                                                 const float* __restrict__ bias,
                                                 float* __restrict__ H, int n) {
  int gid = blockIdx.x * 256 + threadIdx.x;
  int v = gid >> 6;
  int lane = gid & 63;
  if (v >= n) return;
  int g = lane >> 4;           // edge group 0..3
  int sub = lane & 15;         // uint2 index within row (features 4*sub..+3)
  const uint2* __restrict__ T16 = (const uint2*)T;   // 16 uint2 per row
  int beg = rp[v], end = rp[v + 1];

  float4 acc[8];
#pragma unroll
  for (int c = 0; c < 8; c++) acc[c] = make_float4(0.f, 0.f, 0.f, 0.f);
  {  // self loop: exact x0.25 per group (pow2 -> bit-exact sum over 4 groups)
    uint2 w = T16[v * 16 + sub];
    __half2* hp = (__half2*)&w;
    float2 f0 = __half22float2(hp[0]);
    float2 f1 = __half22float2(hp[1]);
    acc[0].x = 0.25f * f0.x; acc[0].y = 0.25f * f0.y;
    acc[0].z = 0.25f * f1.x; acc[0].w = 0.25f * f1.y;
  }
  for (int e = beg; e < end; e += 32) {
    int last = end - 1;
#pragma unroll
    for (int c = 0; c < 8; c++) {
      int i = e + 4 * c + g;
      float m = (i <= last) ? 1.0f : 0.0f;
      int s = col[min(i, last)];
      uint2 w = T16[s * 16 + sub];
      __half2* h = (__half2*)&w;
      float2 f0 = __half22float2(h[0]);
      float2 f1 = __half22float2(h[1]);
      acc[c].x = fmaf(m, f0.x, acc[c].x);
      acc[c].y = fmaf(m, f0.y, acc[c].y);
      acc[c].z = fmaf(m, f1.x, acc[c].z);
      acc[c].w = fmaf(m, f1.y, acc[c].w);
    }
  }
  float4 s01, s23, s45, s67, sA, sB, s;
  s01.x = acc[0].x + acc[1].x; s01.y = acc[0].y + acc[1].y;
  s01.z = acc[0].z + acc[1].z; s01.w = acc[0].w + acc[1].w;
  s23.x = acc[2].x + acc[3].x; s23.y = acc[2].y + acc[3].y;
  s23.z = acc[2].z + acc[3].z; s23.w = acc[2].w + acc[3].w;
  s45.x = acc[4].x + acc[5].x; s45.y = acc[4].y + acc[5].y;
  s45.z = acc[4].z + acc[5].z; s45.w = acc[4].w + acc[5].w;
  s67.x = acc[6].x + acc[7].x; s67.y = acc[6].y + acc[7].y;
  s67.z = acc[6].z + acc[7].z; s67.w = acc[6].w + acc[7].w;
  sA.x = s01.x + s23.x; sA.y = s01.y + s23.y; sA.z = s01.z + s23.z; sA.w = s01.w + s23.w;
  sB.x = s45.x + s67.x; sB.y = s45.y + s67.y; sB.z = s45.z + s67.z; sB.w = s45.w + s67.w;
  s.x = sA.x + sB.x; s.y = sA.y + sB.y; s.z = sA.z + sB.z; s.w = sA.w + sB.w;
  s.x += __shfl_xor(s.x, 16); s.y += __shfl_xor(s.y, 16);
  s.z += __shfl_xor(s.z, 16); s.w += __shfl_xor(s.w, 16);
  s.x += __shfl_xor(s.x, 32); s.y += __shfl_xor(s.y, 32);
  s.z += __shfl_xor(s.z, 32); s.w += __shfl_xor(s.w, 32);
  if (lane < 16) {
    float di = dinv[v];
    float4 b4 = ((const float4*)bias)[sub];
    float4 r;
    r.x = di * s.x + b4.x; r.y = di * s.y + b4.y;
    r.z = di * s.z + b4.z; r.w = di * s.w + b4.w;
    r.x = r.x > 0.f ? r.x : 0.f;
    r.y = r.y > 0.f ? r.y : 0.f;
    r.z = r.z > 0.f ? r.z : 0.f;
    r.w = r.w > 0.f ? r.w : 0.f;
    *(float4*)(H + (size_t)v * HID + sub * 4) = r;
  }
}

// ---------------------------------------------------------------------------
// Fused MLP head: out = relu(H @ Wp1 + bp1) @ Wp2 + bp2, thread-per-node
// ---------------------------------------------------------------------------
__global__ __launch_bounds__(256) void mlp_head(const float* __restrict__ H,
                                                const float* __restrict__ Wp1,
                                                const float* __restrict__ bp1,
                                                const float* __restrict__ Wp2,
                                                const float* __restrict__ bp2,
                                                float* __restrict__ out, int n) {
  __shared__ float W1t[32 * 64];  // transposed: W1t[j*64+k] = Wp1[k*32+j]
  __shared__ float w2s[32];
  __shared__ float b1s[32];
  for (int i = threadIdx.x; i < 64 * 32; i += 256) {
    int k = i >> 5, j = i & 31;
    W1t[j * 64 + k] = Wp1[i];
  }
  if (threadIdx.x < 32) {
    w2s[threadIdx.x] = Wp2[threadIdx.x];
    b1s[threadIdx.x] = bp1[threadIdx.x];
  }
  __syncthreads();
  int node = blockIdx.x * 256 + threadIdx.x;
  if (node >= n) return;
  float4 h[16];
  const float4* __restrict__ hr = (const float4*)(H + (size_t)node * 64);
#pragma unroll
  for (int j = 0; j < 16; j++) h[j] = hr[j];
  float o = bp2[0];
#pragma unroll
  for (int j = 0; j < 32; j++) {
    const float4* wr = (const float4*)(W1t + j * 64);
    float4 a4 = make_float4(0.f, 0.f, 0.f, 0.f);
#pragma unroll
    for (int k = 0; k < 16; k++) {
      float4 w = wr[k];
      a4.x += h[k].x * w.x;
      a4.y += h[k].y * w.y;
      a4.z += h[k].z * w.z;
      a4.w += h[k].w * w.w;
    }
    float a = a4.x + a4.y + a4.z + a4.w + b1s[j];
    a = a > 0.f ? a : 0.f;
    o += a * w2s[j];
  }
  out[node] = o;
}

// ---------------------------------------------------------------------------
extern "C" void kernel_launch(void* const* d_in, const int* in_sizes, int n_in,
                              void* d_out, int out_size, void* d_ws, size_t ws_size,
                              hipStream_t stream) {
  const float* x   = (const float*)d_in[0];
  const int* edge  = (const int*)d_in[1];
  const float* W1  = (const float*)d_in[3];
  const float* b1  = (const float*)d_in[4];
  const float* W2  = (const float*)d_in[5];
  const float* b2  = (const float*)d_in[6];
  const float* W3  = (const float*)d_in[7];
  const float* b3  = (const float*)d_in[8];
  const float* Wp1 = (const float*)d_in[9];
  const float* bp1 = (const float*)d_in[10];
  const float* Wp2 = (const float*)d_in[11];
  const float* bp2 = (const float*)d_in[12];
  float* out = (float*)d_out;

  const int n = in_sizes[0] / NDIM_IN;   // 100000
  const int E = in_sizes[1] / 2;         // 1600000
  const int* src = edge;
  const int* dst = edge + E;

  // workspace carve-out (256B aligned slices)
  char* ws = (char*)d_ws;
  size_t off = 0;
  auto carve = [&](size_t bytes) {
    char* p = ws + off;
    off = (off + bytes + 255) & ~(size_t)255;
    return p;
  };
  int*    histT = (int*)carve((size_t)NB * NC * 4);   // 800 KB
  int*    bsum  = (int*)carve(1024 * 4);
  int*    tmp   = (int*)carve((size_t)E * 4);         // 6.4 MB (packed)
  int*    col   = (int*)carve((size_t)E * 4);         // 6.4 MB
  int*    rp    = (int*)carve(((size_t)n + 1) * 4);
  float*  dinv  = (float*)carve((size_t)n * 4);
  __half* bufT  = (__half*)carve((size_t)n * HID * 2);
  float*  bufA  = (float*)carve((size_t)n * HID * 4);
  (void)ws_size; (void)n_in; (void)out_size;

  const int nbN = (n + 255) / 256;        // 391
  const int nbG = (n + 63) / 64;          // 1563 (gemm: 64 nodes/block)
  const int scan_len = NB * NC;           // 200192
  const int nbScan = (scan_len + 255) / 256;  // 782 == NB (alignment!)

  hist_k<<<NC, 256, 0, stream>>>(dst, histT, E);
  scan1<<<nbScan, 256, 0, stream>>>(histT, bsum, scan_len);
  scan2<<<1, 1024, 0, stream>>>(bsum, nbScan);
  scatter_k<<<NC, 256, 0, stream>>>(src, dst, histT, bsum, tmp, E);
  binsort_k<<<NB, 256, 0, stream>>>(tmp, bsum, col, rp, dinv, n, E);

  const int nbSp = ((n * 64) + 255) / 256;

  // layer 1: 128 -> 64
  gemm_xw<128><<<nbG, 256, 0, stream>>>(x, W1, dinv, bufT, n);
  spmm_relu<<<nbSp, 256, 0, stream>>>(rp, col, bufT, dinv, b1, bufA, n);
  // layer 2: 64 -> 64
  gemm_xw<64><<<nbG, 256, 0, stream>>>(bufA, W2, dinv, bufT, n);
  spmm_relu<<<nbSp, 256, 0, stream>>>(rp, col, bufT, dinv, b2, bufA, n);
  // layer 3: 64 -> 64
  gemm_xw<64><<<nbG, 256, 0, stream>>>(bufA, W3, dinv, bufT, n);
  spmm_relu<<<nbSp, 256, 0, stream>>>(rp, col, bufT, dinv, b3, bufA, n);
  // head
  mlp_head<<<nbN, 256, 0, stream>>>(bufA, Wp1, bp1, Wp2, bp2, out, n);
}

// Round 10
// 351.379 us; speedup vs baseline: 1.0543x; 1.0543x over previous
//
#include <hip/hip_runtime.h>
#include <hip/hip_bf16.h>
#include <hip/hip_fp16.h>

#define NDIM_IN 128
#define HID 64

#define BINW 128          // dst values per bin
#define NB   782          // ceil(100000/128)
#define NC   256          // phase-1 blocks == scan1 block size (alignment!)
#define CAP  3072         // LDS edge buffer per bin (mean 2046, +22 sigma)

// ---------------------------------------------------------------------------
// Phase 1a: per-block LDS histogram over bins, written transposed:
// histT[bin*NC + block]. No global atomics, no memset needed.
// ---------------------------------------------------------------------------
__global__ __launch_bounds__(256) void hist_k(const int* __restrict__ dst,
                                              int* __restrict__ histT, int E) {
  __shared__ int h[NB];
  for (int i = threadIdx.x; i < NB; i += 256) h[i] = 0;
  __syncthreads();
  int E4 = E >> 2;
  int chunk = (E4 + NC - 1) / NC;
  int beg = blockIdx.x * chunk;
  int end = min(E4, beg + chunk);
  const int4* __restrict__ d4 = (const int4*)dst;
  for (int i = beg + (int)threadIdx.x; i < end; i += 256) {
    int4 d = d4[i];
    atomicAdd(&h[d.x >> 7], 1);
    atomicAdd(&h[d.y >> 7], 1);
    atomicAdd(&h[d.z >> 7], 1);
    atomicAdd(&h[d.w >> 7], 1);
  }
  __syncthreads();
  for (int i = threadIdx.x; i < NB; i += 256)
    histT[i * NC + blockIdx.x] = h[i];
}

// ---------------------------------------------------------------------------
// scan1: per-256-block exclusive scan in-place + block sums. Because the
// scan block size == NC, scan-block b covers exactly bin b -> after scan2,
// bsum[bin] IS the global bin base (no scan3 pass needed).
// ---------------------------------------------------------------------------
__global__ __launch_bounds__(256) void scan1(int* __restrict__ g,
                                             int* __restrict__ bs, int len) {
  __shared__ int s[256];
  int t = threadIdx.x;
  int i = blockIdx.x * 256 + t;
  int v = (i < len) ? g[i] : 0;
  s[t] = v;
  __syncthreads();
  for (int off = 1; off < 256; off <<= 1) {
    int x = (t >= off) ? s[t - off] : 0;
    __syncthreads();
    s[t] += x;
    __syncthreads();
  }
  if (i < len) g[i] = s[t] - v;          // exclusive within block
  if (t == 255) bs[blockIdx.x] = s[255];
}

__global__ __launch_bounds__(1024) void scan2(int* __restrict__ bs, int nb) {
  __shared__ int s[1024];
  int t = threadIdx.x;
  int v = (t < nb) ? bs[t] : 0;
  s[t] = v;
  __syncthreads();
  for (int off = 1; off < 1024; off <<= 1) {
    int x = (t >= off) ? s[t - off] : 0;
    __syncthreads();
    s[t] += x;
    __syncthreads();
  }
  if (t < nb) bs[t] = s[t] - v;          // exclusive bin bases
}

// ---------------------------------------------------------------------------
// Phase 1c: scatter packed (src<<7 | dst&127) into tmp, grouped by bin.
// LDS cursor seed = within-bin partial (S) + global bin base (bsum).
// ---------------------------------------------------------------------------
__global__ __launch_bounds__(256) void scatter_k(const int* __restrict__ src,
                                                 const int* __restrict__ dst,
                                                 const int* __restrict__ S,
                                                 const int* __restrict__ bsum,
                                                 int* __restrict__ tmp, int E) {
  __shared__ int cur[NB];
  for (int i = threadIdx.x; i < NB; i += 256)
    cur[i] = S[i * NC + blockIdx.x] + bsum[i];
  __syncthreads();
  int E4 = E >> 2;
  int chunk = (E4 + NC - 1) / NC;
  int beg = blockIdx.x * chunk;
  int end = min(E4, beg + chunk);
  const int4* __restrict__ d4 = (const int4*)dst;
  const int4* __restrict__ s4 = (const int4*)src;
  for (int i = beg + (int)threadIdx.x; i < end; i += 256) {
    int4 d = d4[i];
    int4 sv = s4[i];
    int p0 = atomicAdd(&cur[d.x >> 7], 1); tmp[p0] = (sv.x << 7) | (d.x & 127);
    int p1 = atomicAdd(&cur[d.y >> 7], 1); tmp[p1] = (sv.y << 7) | (d.y & 127);
    int p2 = atomicAdd(&cur[d.z >> 7], 1); tmp[p2] = (sv.z << 7) | (d.z & 127);
    int p3 = atomicAdd(&cur[d.w >> 7], 1); tmp[p3] = (sv.w << 7) | (d.w & 127);
  }
}

// ---------------------------------------------------------------------------
// Phase 2: one block per bin. Exact in-LDS counting sort by dst within the
// bin; emits col (coalesced), rp, and dinv. All atomics are LDS.
// ---------------------------------------------------------------------------
__global__ __launch_bounds__(256) void binsort_k(const int* __restrict__ tmp,
                                                 const int* __restrict__ bsum,
                                                 int* __restrict__ col,
                                                 int* __restrict__ rp,
                                                 float* __restrict__ dinv,
                                                 int n, int E) {
  int bin = blockIdx.x;
  int base = bsum[bin];
  int end = (bin == NB - 1) ? E : bsum[bin + 1];
  int m = end - base;
  __shared__ int cnt[BINW];
  __shared__ int offs[BINW];
  __shared__ int cur[BINW];
  __shared__ int buf[CAP];
  int t = threadIdx.x;
  if (t < BINW) cnt[t] = 0;
  __syncthreads();
  for (int i = t; i < m; i += 256) {
    int p = tmp[base + i];
    atomicAdd(&cnt[p & (BINW - 1)], 1);
  }
  __syncthreads();
  if (t < BINW) offs[t] = cnt[t];
  __syncthreads();
  for (int off = 1; off < BINW; off <<= 1) {
    int x = (t < BINW && t >= off) ? offs[t - off] : 0;
    __syncthreads();
    if (t < BINW) offs[t] += x;
    __syncthreads();
  }
  if (t < BINW) {
    int ex = offs[t] - cnt[t];             // exclusive
    cur[t] = ex;
    int v = bin * BINW + t;
    if (v < n) {
      rp[v] = base + ex;
      dinv[v] = rsqrtf((float)cnt[t] + 1.0f);  // +1 = self loop
    }
  }
  if (bin == NB - 1 && t == 0) rp[n] = E;
  __syncthreads();
  for (int i = t; i < m; i += 256) {
    int p = tmp[base + i];
    int r = atomicAdd(&cur[p & (BINW - 1)], 1);
    if (r < CAP) buf[r] = p >> 7;          // unpacked src
  }
  __syncthreads();
  int mm = min(m, CAP);
  for (int i = t; i < mm; i += 256) col[base + i] = buf[i];
}

// ---------------------------------------------------------------------------
// Dense transform T' = (X @ W) * dinv[row], output fp16.
// Block = 256 threads = 64 nodes x 4 out-groups (og wave-uniform; 16 outs).
// X staged in LDS (stride K+1); W via wave-uniform addresses -> s_load.
// ---------------------------------------------------------------------------
template <int K>
__global__ __launch_bounds__(256) void gemm_xw(const float* __restrict__ X,
                                               const float* __restrict__ W,
                                               const float* __restrict__ dinv,
                                               __half* __restrict__ T, int n) {
  constexpr int STR = K + 1;
  constexpr int RF4 = K / 4;  // float4 per row
  __shared__ float Xs[64 * STR];
  int t = threadIdx.x;
  int node0 = blockIdx.x * 64;
  for (int i = t; i < 64 * RF4; i += 256) {
    int r = i / RF4, c = i % RF4;
    int node = node0 + r;
    float4 v = make_float4(0.f, 0.f, 0.f, 0.f);
    if (node < n) v = *(const float4*)(X + (size_t)node * K + c * 4);
    float* p = &Xs[r * STR + c * 4];
    p[0] = v.x; p[1] = v.y; p[2] = v.z; p[3] = v.w;
  }
  __syncthreads();
  int lane = t & 63;
  int og = __builtin_amdgcn_readfirstlane(t >> 6);  // wave-uniform out-group
  int node = node0 + lane;
  const float* __restrict__ Wg = W + og * 16;       // uniform -> s_load
  const float* __restrict__ xrow = &Xs[lane * STR];
  float4 a0 = make_float4(0.f, 0.f, 0.f, 0.f);
  float4 a1 = make_float4(0.f, 0.f, 0.f, 0.f);
  float4 a2 = make_float4(0.f, 0.f, 0.f, 0.f);
  float4 a3 = make_float4(0.f, 0.f, 0.f, 0.f);
#pragma unroll 4
  for (int k = 0; k < K; k++) {
    float xk = xrow[k];
    const float* __restrict__ wk = Wg + k * 64;
    a0.x += xk * wk[0];  a0.y += xk * wk[1];  a0.z += xk * wk[2];  a0.w += xk * wk[3];
    a1.x += xk * wk[4];  a1.y += xk * wk[5];  a1.z += xk * wk[6];  a1.w += xk * wk[7];
    a2.x += xk * wk[8];  a2.y += xk * wk[9];  a2.z += xk * wk[10]; a2.w += xk * wk[11];
    a3.x += xk * wk[12]; a3.y += xk * wk[13]; a3.z += xk * wk[14]; a3.w += xk * wk[15];
  }
  if (node >= n) return;
  float di = dinv[node];
  __half2 h0 = __floats2half2_rn(a0.x * di, a0.y * di);
  __half2 h1 = __floats2half2_rn(a0.z * di, a0.w * di);
  __half2 h2 = __floats2half2_rn(a1.x * di, a1.y * di);
  __half2 h3 = __floats2half2_rn(a1.z * di, a1.w * di);
  __half2 h4 = __floats2half2_rn(a2.x * di, a2.y * di);
  __half2 h5 = __floats2half2_rn(a2.z * di, a2.w * di);
  __half2 h6 = __floats2half2_rn(a3.x * di, a3.y * di);
  __half2 h7 = __floats2half2_rn(a3.z * di, a3.w * di);
  uint4* __restrict__ o = (uint4*)(T + (size_t)node * 64 + og * 16);
  uint4 p0, p1;
  p0.x = *(unsigned int*)&h0; p0.y = *(unsigned int*)&h1;
  p0.z = *(unsigned int*)&h2; p0.w = *(unsigned int*)&h3;
  p1.x = *(unsigned int*)&h4; p1.y = *(unsigned int*)&h5;
  p1.z = *(unsigned int*)&h6; p1.w = *(unsigned int*)&h7;
  o[0] = p0;
  o[1] = p1;
}

// ---------------------------------------------------------------------------
// SpMM gather: wave-per-node, 8 groups x 8 lanes, uint4 per lane (8 lanes x
// 16B = full 128B row). ONE gather instruction covers 8 distinct edges; the
// 2x unroll puts 16 edges (~= full Poisson-16 degree) in flight from just
// 4 VMEM instructions (2 col broadcasts + 2 row gathers) -> one latency
// round for ~50% of nodes, minimal issue slots per edge. Maskless main loop
// (multiple of 16), exec-guarded tail, self-loop added by group 0 exactly
// once. Combine: xor-shuffle 8/16/32; lanes 0-7 write 2x float4.
// ---------------------------------------------------------------------------
__global__ __launch_bounds__(256) void spmm_relu(const int* __restrict__ rp,
                                                 const int* __restrict__ col,
                                                 const __half* __restrict__ T,
                                                 const float* __restrict__ dinv,
                                                 const float* __restrict__ bias,
                                                 float* __restrict__ H, int n) {
  int gid = blockIdx.x * 256 + threadIdx.x;
  int v = gid >> 6;
  int lane = gid & 63;
  if (v >= n) return;
  int g = lane >> 3;           // edge group 0..7
  int sub = lane & 7;          // uint4 index within row (features 8*sub..+7)
  const uint4* __restrict__ T8 = (const uint4*)T;   // 8 uint4 per row
  int beg = rp[v], end = rp[v + 1];

  float a0[8], a1[8];
#pragma unroll
  for (int j = 0; j < 8; j++) { a0[j] = 0.f; a1[j] = 0.f; }

  if (g == 0) {  // self loop: group 0 adds T'[v] exactly once
    uint4 w = T8[v * 8 + sub];
    const __half2* h = (const __half2*)&w;
#pragma unroll
    for (int j = 0; j < 4; j++) {
      float2 f = __half22float2(h[j]);
      a0[2 * j] += f.x; a0[2 * j + 1] += f.y;
    }
  }
  int efull = beg + ((end - beg) & ~15);
  for (int e = beg; e < efull; e += 16) {
    int s0 = col[e + g];          // broadcast within group
    int s1 = col[e + 8 + g];
    uint4 w0 = T8[s0 * 8 + sub];  // 8 lanes = full row; 8 groups = 8 rows
    uint4 w1 = T8[s1 * 8 + sub];
    const __half2* h0 = (const __half2*)&w0;
    const __half2* h1 = (const __half2*)&w1;
#pragma unroll
    for (int j = 0; j < 4; j++) {
      float2 f0 = __half22float2(h0[j]);
      float2 f1 = __half22float2(h1[j]);
      a0[2 * j] += f0.x; a0[2 * j + 1] += f0.y;
      a1[2 * j] += f1.x; a1[2 * j + 1] += f1.y;
    }
  }
  {  // tail (<16 edges): 2 exec-guarded rounds
    int i0 = efull + g, i1 = efull + 8 + g;
    if (i0 < end) {
      uint4 w = T8[col[i0] * 8 + sub];
      const __half2* h = (const __half2*)&w;
#pragma unroll
      for (int j = 0; j < 4; j++) {
        float2 f = __half22float2(h[j]);
        a0[2 * j] += f.x; a0[2 * j + 1] += f.y;
      }
    }
    if (i1 < end) {
      uint4 w = T8[col[i1] * 8 + sub];
      const __half2* h = (const __half2*)&w;
#pragma unroll
      for (int j = 0; j < 4; j++) {
        float2 f = __half22float2(h[j]);
        a1[2 * j] += f.x; a1[2 * j + 1] += f.y;
      }
    }
  }
  float s[8];
#pragma unroll
  for (int j = 0; j < 8; j++) s[j] = a0[j] + a1[j];
#pragma unroll
  for (int j = 0; j < 8; j++) s[j] += __shfl_xor(s[j], 8);
#pragma unroll
  for (int j = 0; j < 8; j++) s[j] += __shfl_xor(s[j], 16);
#pragma unroll
  for (int j = 0; j < 8; j++) s[j] += __shfl_xor(s[j], 32);
  if (lane < 8) {
    float di = dinv[v];
    const float4* __restrict__ b4 = (const float4*)bias;
    float4 bA = b4[sub * 2], bB = b4[sub * 2 + 1];
    float4 rA, rB;
    rA.x = di * s[0] + bA.x; rA.y = di * s[1] + bA.y;
    rA.z = di * s[2] + bA.z; rA.w = di * s[3] + bA.w;
    rB.x = di * s[4] + bB.x; rB.y = di * s[5] + bB.y;
    rB.z = di * s[6] + bB.z; rB.w = di * s[7] + bB.w;
    rA.x = rA.x > 0.f ? rA.x : 0.f;  rA.y = rA.y > 0.f ? rA.y : 0.f;
    rA.z = rA.z > 0.f ? rA.z : 0.f;  rA.w = rA.w > 0.f ? rA.w : 0.f;
    rB.x = rB.x > 0.f ? rB.x : 0.f;  rB.y = rB.y > 0.f ? rB.y : 0.f;
    rB.z = rB.z > 0.f ? rB.z : 0.f;  rB.w = rB.w > 0.f ? rB.w : 0.f;
    float4* __restrict__ o = (float4*)(H + (size_t)v * HID + sub * 8);
    o[0] = rA;
    o[1] = rB;
  }
}

// ---------------------------------------------------------------------------
// Fused MLP head: out = relu(H @ Wp1 + bp1) @ Wp2 + bp2, thread-per-node
// ---------------------------------------------------------------------------
__global__ __launch_bounds__(256) void mlp_head(const float* __restrict__ H,
                                                const float* __restrict__ Wp1,
                                                const float* __restrict__ bp1,
                                                const float* __restrict__ Wp2,
                                                const float* __restrict__ bp2,
                                                float* __restrict__ out, int n) {
  __shared__ float W1t[32 * 64];  // transposed: W1t[j*64+k] = Wp1[k*32+j]
  __shared__ float w2s[32];
  __shared__ float b1s[32];
  for (int i = threadIdx.x; i < 64 * 32; i += 256) {
    int k = i >> 5, j = i & 31;
    W1t[j * 64 + k] = Wp1[i];
  }
  if (threadIdx.x < 32) {
    w2s[threadIdx.x] = Wp2[threadIdx.x];
    b1s[threadIdx.x] = bp1[threadIdx.x];
  }
  __syncthreads();
  int node = blockIdx.x * 256 + threadIdx.x;
  if (node >= n) return;
  float4 h[16];
  const float4* __restrict__ hr = (const float4*)(H + (size_t)node * 64);
#pragma unroll
  for (int j = 0; j < 16; j++) h[j] = hr[j];
  float o = bp2[0];
#pragma unroll
  for (int j = 0; j < 32; j++) {
    const float4* wr = (const float4*)(W1t + j * 64);
    float4 a4 = make_float4(0.f, 0.f, 0.f, 0.f);
#pragma unroll
    for (int k = 0; k < 16; k++) {
      float4 w = wr[k];
      a4.x += h[k].x * w.x;
      a4.y += h[k].y * w.y;
      a4.z += h[k].z * w.z;
      a4.w += h[k].w * w.w;
    }
    float a = a4.x + a4.y + a4.z + a4.w + b1s[j];
    a = a > 0.f ? a : 0.f;
    o += a * w2s[j];
  }
  out[node] = o;
}

// ---------------------------------------------------------------------------
extern "C" void kernel_launch(void* const* d_in, const int* in_sizes, int n_in,
                              void* d_out, int out_size, void* d_ws, size_t ws_size,
                              hipStream_t stream) {
  const float* x   = (const float*)d_in[0];
  const int* edge  = (const int*)d_in[1];
  const float* W1  = (const float*)d_in[3];
  const float* b1  = (const float*)d_in[4];
  const float* W2  = (const float*)d_in[5];
  const float* b2  = (const float*)d_in[6];
  const float* W3  = (const float*)d_in[7];
  const float* b3  = (const float*)d_in[8];
  const float* Wp1 = (const float*)d_in[9];
  const float* bp1 = (const float*)d_in[10];
  const float* Wp2 = (const float*)d_in[11];
  const float* bp2 = (const float*)d_in[12];
  float* out = (float*)d_out;

  const int n = in_sizes[0] / NDIM_IN;   // 100000
  const int E = in_sizes[1] / 2;         // 1600000
  const int* src = edge;
  const int* dst = edge + E;

  // workspace carve-out (256B aligned slices)
  char* ws = (char*)d_ws;
  size_t off = 0;
  auto carve = [&](size_t bytes) {
    char* p = ws + off;
    off = (off + bytes + 255) & ~(size_t)255;
    return p;
  };
  int*    histT = (int*)carve((size_t)NB * NC * 4);   // 800 KB
  int*    bsum  = (int*)carve(1024 * 4);
  int*    tmp   = (int*)carve((size_t)E * 4);         // 6.4 MB (packed)
  int*    col   = (int*)carve((size_t)E * 4);         // 6.4 MB
  int*    rp    = (int*)carve(((size_t)n + 1) * 4);
  float*  dinv  = (float*)carve((size_t)n * 4);
  __half* bufT  = (__half*)carve((size_t)n * HID * 2);
  float*  bufA  = (float*)carve((size_t)n * HID * 4);
  (void)ws_size; (void)n_in; (void)out_size;

  const int nbN = (n + 255) / 256;        // 391
  const int nbG = (n + 63) / 64;          // 1563 (gemm: 64 nodes/block)
  const int scan_len = NB * NC;           // 200192
  const int nbScan = (scan_len + 255) / 256;  // 782 == NB (alignment!)

  hist_k<<<NC, 256, 0, stream>>>(dst, histT, E);
  scan1<<<nbScan, 256, 0, stream>>>(histT, bsum, scan_len);
  scan2<<<1, 1024, 0, stream>>>(bsum, nbScan);
  scatter_k<<<NC, 256, 0, stream>>>(src, dst, histT, bsum, tmp, E);
  binsort_k<<<NB, 256, 0, stream>>>(tmp, bsum, col, rp, dinv, n, E);

  const int nbSp = ((n * 64) + 255) / 256;

  // layer 1: 128 -> 64
  gemm_xw<128><<<nbG, 256, 0, stream>>>(x, W1, dinv, bufT, n);
  spmm_relu<<<nbSp, 256, 0, stream>>>(rp, col, bufT, dinv, b1, bufA, n);
  // layer 2: 64 -> 64
  gemm_xw<64><<<nbG, 256, 0, stream>>>(bufA, W2, dinv, bufT, n);
  spmm_relu<<<nbSp, 256, 0, stream>>>(rp, col, bufT, dinv, b2, bufA, n);
  // layer 3: 64 -> 64
  gemm_xw<64><<<nbG, 256, 0, stream>>>(bufA, W3, dinv, bufT, n);
  spmm_relu<<<nbSp, 256, 0, stream>>>(rp, col, bufT, dinv, b3, bufA, n);
  // head
  mlp_head<<<nbN, 256, 0, stream>>>(bufA, Wp1, bp1, Wp2, bp2, out, n);
}

// Round 11
// 326.340 us; speedup vs baseline: 1.1352x; 1.0767x over previous
//
#include <hip/hip_runtime.h>
#include <hip/hip_bf16.h>
#include <hip/hip_fp16.h>

#define NDIM_IN 128
#define HID 64

#define BINW 128          // dst values per bin
#define NB   782          // ceil(100000/128)
#define NC   256          // phase-1 blocks == scan1 block size (alignment!)
#define CAP  3072         // LDS edge buffer per bin (mean 2046, +22 sigma)

typedef _Float16 f16x8 __attribute__((ext_vector_type(8)));
typedef float f32x4 __attribute__((ext_vector_type(4)));

// ---------------------------------------------------------------------------
// Phase 1a: per-block LDS histogram over bins, written transposed.
// ---------------------------------------------------------------------------
__global__ __launch_bounds__(256) void hist_k(const int* __restrict__ dst,
                                              int* __restrict__ histT, int E) {
  __shared__ int h[NB];
  for (int i = threadIdx.x; i < NB; i += 256) h[i] = 0;
  __syncthreads();
  int E4 = E >> 2;
  int chunk = (E4 + NC - 1) / NC;
  int beg = blockIdx.x * chunk;
  int end = min(E4, beg + chunk);
  const int4* __restrict__ d4 = (const int4*)dst;
  for (int i = beg + (int)threadIdx.x; i < end; i += 256) {
    int4 d = d4[i];
    atomicAdd(&h[d.x >> 7], 1);
    atomicAdd(&h[d.y >> 7], 1);
    atomicAdd(&h[d.z >> 7], 1);
    atomicAdd(&h[d.w >> 7], 1);
  }
  __syncthreads();
  for (int i = threadIdx.x; i < NB; i += 256)
    histT[i * NC + blockIdx.x] = h[i];
}

// ---------------------------------------------------------------------------
// scan1/scan2: block size == NC so bsum[bin] becomes the global bin base.
// ---------------------------------------------------------------------------
__global__ __launch_bounds__(256) void scan1(int* __restrict__ g,
                                             int* __restrict__ bs, int len) {
  __shared__ int s[256];
  int t = threadIdx.x;
  int i = blockIdx.x * 256 + t;
  int v = (i < len) ? g[i] : 0;
  s[t] = v;
  __syncthreads();
  for (int off = 1; off < 256; off <<= 1) {
    int x = (t >= off) ? s[t - off] : 0;
    __syncthreads();
    s[t] += x;
    __syncthreads();
  }
  if (i < len) g[i] = s[t] - v;
  if (t == 255) bs[blockIdx.x] = s[255];
}

__global__ __launch_bounds__(1024) void scan2(int* __restrict__ bs, int nb) {
  __shared__ int s[1024];
  int t = threadIdx.x;
  int v = (t < nb) ? bs[t] : 0;
  s[t] = v;
  __syncthreads();
  for (int off = 1; off < 1024; off <<= 1) {
    int x = (t >= off) ? s[t - off] : 0;
    __syncthreads();
    s[t] += x;
    __syncthreads();
  }
  if (t < nb) bs[t] = s[t] - v;
}

// ---------------------------------------------------------------------------
// Phase 1c: scatter packed (src<<7 | dst&127) into tmp, grouped by bin.
// ---------------------------------------------------------------------------
__global__ __launch_bounds__(256) void scatter_k(const int* __restrict__ src,
                                                 const int* __restrict__ dst,
                                                 const int* __restrict__ S,
                                                 const int* __restrict__ bsum,
                                                 int* __restrict__ tmp, int E) {
  __shared__ int cur[NB];
  for (int i = threadIdx.x; i < NB; i += 256)
    cur[i] = S[i * NC + blockIdx.x] + bsum[i];
  __syncthreads();
  int E4 = E >> 2;
  int chunk = (E4 + NC - 1) / NC;
  int beg = blockIdx.x * chunk;
  int end = min(E4, beg + chunk);
  const int4* __restrict__ d4 = (const int4*)dst;
  const int4* __restrict__ s4 = (const int4*)src;
  for (int i = beg + (int)threadIdx.x; i < end; i += 256) {
    int4 d = d4[i];
    int4 sv = s4[i];
    int p0 = atomicAdd(&cur[d.x >> 7], 1); tmp[p0] = (sv.x << 7) | (d.x & 127);
    int p1 = atomicAdd(&cur[d.y >> 7], 1); tmp[p1] = (sv.y << 7) | (d.y & 127);
    int p2 = atomicAdd(&cur[d.z >> 7], 1); tmp[p2] = (sv.z << 7) | (d.z & 127);
    int p3 = atomicAdd(&cur[d.w >> 7], 1); tmp[p3] = (sv.w << 7) | (d.w & 127);
  }
}

// ---------------------------------------------------------------------------
// Phase 2: one block per bin; in-LDS counting sort -> col, rp, dinv.
// ---------------------------------------------------------------------------
__global__ __launch_bounds__(256) void binsort_k(const int* __restrict__ tmp,
                                                 const int* __restrict__ bsum,
                                                 int* __restrict__ col,
                                                 int* __restrict__ rp,
                                                 float* __restrict__ dinv,
                                                 int n, int E) {
  int bin = blockIdx.x;
  int base = bsum[bin];
  int end = (bin == NB - 1) ? E : bsum[bin + 1];
  int m = end - base;
  __shared__ int cnt[BINW];
  __shared__ int offs[BINW];
  __shared__ int cur[BINW];
  __shared__ int buf[CAP];
  int t = threadIdx.x;
  if (t < BINW) cnt[t] = 0;
  __syncthreads();
  for (int i = t; i < m; i += 256) {
    int p = tmp[base + i];
    atomicAdd(&cnt[p & (BINW - 1)], 1);
  }
  __syncthreads();
  if (t < BINW) offs[t] = cnt[t];
  __syncthreads();
  for (int off = 1; off < BINW; off <<= 1) {
    int x = (t < BINW && t >= off) ? offs[t - off] : 0;
    __syncthreads();
    if (t < BINW) offs[t] += x;
    __syncthreads();
  }
  if (t < BINW) {
    int ex = offs[t] - cnt[t];
    cur[t] = ex;
    int v = bin * BINW + t;
    if (v < n) {
      rp[v] = base + ex;
      dinv[v] = rsqrtf((float)cnt[t] + 1.0f);  // +1 = self loop
    }
  }
  if (bin == NB - 1 && t == 0) rp[n] = E;
  __syncthreads();
  for (int i = t; i < m; i += 256) {
    int p = tmp[base + i];
    int r = atomicAdd(&cur[p & (BINW - 1)], 1);
    if (r < CAP) buf[r] = p >> 7;
  }
  __syncthreads();
  int mm = min(m, CAP);
  for (int i = t; i < mm; i += 256) col[base + i] = buf[i];
}

// ---------------------------------------------------------------------------
// MFMA dense transform: T' = (X @ W) * dinv[row], output fp16.
// mfma_f32_16x16x32_f16; W stationary in VGPR B-frags (loaded once/wave,
// f32->fp16). Per wave: 16-node tile x 64 outs = 4 N-tiles x (K/32) chunks.
// Layouts (verified m89/m91/m120): A[m=lane&15][k=quad*8+j],
// B[k=quad*8+j][n=lane&15], D[row=quad*4+r][col=lane&15].
// Epilogue: dinv + transpose via stride-68 LDS (2-way banks free, b128 ok).
// ---------------------------------------------------------------------------
template <int K>
__global__ __launch_bounds__(256) void gemm_mfma(const float* __restrict__ X,
                                                 const float* __restrict__ W,
                                                 const float* __restrict__ dinv,
                                                 __half* __restrict__ T,
                                                 int n, int ntiles) {
  constexpr int NCH = K / 32;
  __shared__ float Ds[4][16 * 68];
  int wv = threadIdx.x >> 6;
  int lane = threadIdx.x & 63;
  int colx = lane & 15;
  int quad = lane >> 4;

  // B fragments: whole W, fp16, stationary
  f16x8 bf[4][NCH];
#pragma unroll
  for (int t = 0; t < 4; t++)
#pragma unroll
    for (int c = 0; c < NCH; c++) {
      f16x8 b;
#pragma unroll
      for (int j = 0; j < 8; j++)
        b[j] = (_Float16)W[(32 * c + quad * 8 + j) * 64 + 16 * t + colx];
      bf[t][c] = b;
    }

  for (int tile = blockIdx.x * 4 + wv; tile < ntiles; tile += gridDim.x * 4) {
    int node0 = tile * 16;
    f32x4 acc[4] = {{0.f, 0.f, 0.f, 0.f}, {0.f, 0.f, 0.f, 0.f},
                    {0.f, 0.f, 0.f, 0.f}, {0.f, 0.f, 0.f, 0.f}};
    int arow = min(node0 + colx, n - 1);
    const float* __restrict__ xr = X + (size_t)arow * K;
#pragma unroll
    for (int c = 0; c < NCH; c++) {
      float4 x0 = *(const float4*)(xr + 32 * c + quad * 8);
      float4 x1 = *(const float4*)(xr + 32 * c + quad * 8 + 4);
      f16x8 a;
      a[0] = (_Float16)x0.x; a[1] = (_Float16)x0.y;
      a[2] = (_Float16)x0.z; a[3] = (_Float16)x0.w;
      a[4] = (_Float16)x1.x; a[5] = (_Float16)x1.y;
      a[6] = (_Float16)x1.z; a[7] = (_Float16)x1.w;
#pragma unroll
      for (int t = 0; t < 4; t++)
        acc[t] = __builtin_amdgcn_mfma_f32_16x16x32_f16(a, bf[t][c], acc[t], 0, 0, 0);
    }
    // epilogue: scale rows by dinv, transpose through LDS, emit fp16
    float dv[4];
#pragma unroll
    for (int r = 0; r < 4; r++) {
      int nd = min(node0 + quad * 4 + r, n - 1);
      dv[r] = dinv[nd];
    }
#pragma unroll
    for (int t = 0; t < 4; t++)
#pragma unroll
      for (int r = 0; r < 4; r++)
        Ds[wv][(quad * 4 + r) * 68 + 16 * t + colx] = acc[t][r] * dv[r];
    // read back: lane covers node=colx, outs quad*16..+15
    int nd = node0 + colx;
    const float* __restrict__ row = &Ds[wv][colx * 68 + quad * 16];
    float4 y0 = *(const float4*)(row + 0);
    float4 y1 = *(const float4*)(row + 4);
    float4 y2 = *(const float4*)(row + 8);
    float4 y3 = *(const float4*)(row + 12);
    f16x8 o0, o1;
    o0[0] = (_Float16)y0.x; o0[1] = (_Float16)y0.y;
    o0[2] = (_Float16)y0.z; o0[3] = (_Float16)y0.w;
    o0[4] = (_Float16)y1.x; o0[5] = (_Float16)y1.y;
    o0[6] = (_Float16)y1.z; o0[7] = (_Float16)y1.w;
    o1[0] = (_Float16)y2.x; o1[1] = (_Float16)y2.y;
    o1[2] = (_Float16)y2.z; o1[3] = (_Float16)y2.w;
    o1[4] = (_Float16)y3.x; o1[5] = (_Float16)y3.y;
    o1[6] = (_Float16)y3.z; o1[7] = (_Float16)y3.w;
    if (nd < n) {
      uint4* __restrict__ o = (uint4*)(T + (size_t)nd * 64 + quad * 16);
      o[0] = *(uint4*)&o0;
      o[1] = *(uint4*)&o1;
    }
  }
}

// ---------------------------------------------------------------------------
// SpMM gather: wave-per-node, 8 groups x 8 lanes, uint4 per lane (8 lanes x
// 16B = full 128B row). 2x unroll = 16 edges in flight from 4 VMEM instrs.
// (R10 winner — frozen.)
// ---------------------------------------------------------------------------
__global__ __launch_bounds__(256) void spmm_relu(const int* __restrict__ rp,
                                                 const int* __restrict__ col,
                                                 const __half* __restrict__ T,
                                                 const float* __restrict__ dinv,
                                                 const float* __restrict__ bias,
                                                 float* __restrict__ H, int n) {
  int gid = blockIdx.x * 256 + threadIdx.x;
  int v = gid >> 6;
  int lane = gid & 63;
  if (v >= n) return;
  int g = lane >> 3;
  int sub = lane & 7;
  const uint4* __restrict__ T8 = (const uint4*)T;
  int beg = rp[v], end = rp[v + 1];

  float a0[8], a1[8];
#pragma unroll
  for (int j = 0; j < 8; j++) { a0[j] = 0.f; a1[j] = 0.f; }

  if (g == 0) {
    uint4 w = T8[v * 8 + sub];
    const __half2* h = (const __half2*)&w;
#pragma unroll
    for (int j = 0; j < 4; j++) {
      float2 f = __half22float2(h[j]);
      a0[2 * j] += f.x; a0[2 * j + 1] += f.y;
    }
  }
  int efull = beg + ((end - beg) & ~15);
  for (int e = beg; e < efull; e += 16) {
    int s0 = col[e + g];
    int s1 = col[e + 8 + g];
    uint4 w0 = T8[s0 * 8 + sub];
    uint4 w1 = T8[s1 * 8 + sub];
    const __half2* h0 = (const __half2*)&w0;
    const __half2* h1 = (const __half2*)&w1;
#pragma unroll
    for (int j = 0; j < 4; j++) {
      float2 f0 = __half22float2(h0[j]);
      float2 f1 = __half22float2(h1[j]);
      a0[2 * j] += f0.x; a0[2 * j + 1] += f0.y;
      a1[2 * j] += f1.x; a1[2 * j + 1] += f1.y;
    }
  }
  {
    int i0 = efull + g, i1 = efull + 8 + g;
    if (i0 < end) {
      uint4 w = T8[col[i0] * 8 + sub];
      const __half2* h = (const __half2*)&w;
#pragma unroll
      for (int j = 0; j < 4; j++) {
        float2 f = __half22float2(h[j]);
        a0[2 * j] += f.x; a0[2 * j + 1] += f.y;
      }
    }
    if (i1 < end) {
      uint4 w = T8[col[i1] * 8 + sub];
      const __half2* h = (const __half2*)&w;
#pragma unroll
      for (int j = 0; j < 4; j++) {
        float2 f = __half22float2(h[j]);
        a1[2 * j] += f.x; a1[2 * j + 1] += f.y;
      }
    }
  }
  float s[8];
#pragma unroll
  for (int j = 0; j < 8; j++) s[j] = a0[j] + a1[j];
#pragma unroll
  for (int j = 0; j < 8; j++) s[j] += __shfl_xor(s[j], 8);
#pragma unroll
  for (int j = 0; j < 8; j++) s[j] += __shfl_xor(s[j], 16);
#pragma unroll
  for (int j = 0; j < 8; j++) s[j] += __shfl_xor(s[j], 32);
  if (lane < 8) {
    float di = dinv[v];
    const float4* __restrict__ b4 = (const float4*)bias;
    float4 bA = b4[sub * 2], bB = b4[sub * 2 + 1];
    float4 rA, rB;
    rA.x = di * s[0] + bA.x; rA.y = di * s[1] + bA.y;
    rA.z = di * s[2] + bA.z; rA.w = di * s[3] + bA.w;
    rB.x = di * s[4] + bB.x; rB.y = di * s[5] + bB.y;
    rB.z = di * s[6] + bB.z; rB.w = di * s[7] + bB.w;
    rA.x = rA.x > 0.f ? rA.x : 0.f;  rA.y = rA.y > 0.f ? rA.y : 0.f;
    rA.z = rA.z > 0.f ? rA.z : 0.f;  rA.w = rA.w > 0.f ? rA.w : 0.f;
    rB.x = rB.x > 0.f ? rB.x : 0.f;  rB.y = rB.y > 0.f ? rB.y : 0.f;
    rB.z = rB.z > 0.f ? rB.z : 0.f;  rB.w = rB.w > 0.f ? rB.w : 0.f;
    float4* __restrict__ o = (float4*)(H + (size_t)v * HID + sub * 8);
    o[0] = rA;
    o[1] = rB;
  }
}

// ---------------------------------------------------------------------------
// Fused MLP head: out = relu(H @ Wp1 + bp1) @ Wp2 + bp2, thread-per-node
// ---------------------------------------------------------------------------
__global__ __launch_bounds__(256) void mlp_head(const float* __restrict__ H,
                                                const float* __restrict__ Wp1,
                                                const float* __restrict__ bp1,
                                                const float* __restrict__ Wp2,
                                                const float* __restrict__ bp2,
                                                float* __restrict__ out, int n) {
  __shared__ float W1t[32 * 64];
  __shared__ float w2s[32];
  __shared__ float b1s[32];
  for (int i = threadIdx.x; i < 64 * 32; i += 256) {
    int k = i >> 5, j = i & 31;
    W1t[j * 64 + k] = Wp1[i];
  }
  if (threadIdx.x < 32) {
    w2s[threadIdx.x] = Wp2[threadIdx.x];
    b1s[threadIdx.x] = bp1[threadIdx.x];
  }
  __syncthreads();
  int node = blockIdx.x * 256 + threadIdx.x;
  if (node >= n) return;
  float4 h[16];
  const float4* __restrict__ hr = (const float4*)(H + (size_t)node * 64);
#pragma unroll
  for (int j = 0; j < 16; j++) h[j] = hr[j];
  float o = bp2[0];
#pragma unroll
  for (int j = 0; j < 32; j++) {
    const float4* wr = (const float4*)(W1t + j * 64);
    float4 a4 = make_float4(0.f, 0.f, 0.f, 0.f);
#pragma unroll
    for (int k = 0; k < 16; k++) {
      float4 w = wr[k];
      a4.x += h[k].x * w.x;
      a4.y += h[k].y * w.y;
      a4.z += h[k].z * w.z;
      a4.w += h[k].w * w.w;
    }
    float a = a4.x + a4.y + a4.z + a4.w + b1s[j];
    a = a > 0.f ? a : 0.f;
    o += a * w2s[j];
  }
  out[node] = o;
}

// ---------------------------------------------------------------------------
extern "C" void kernel_launch(void* const* d_in, const int* in_sizes, int n_in,
                              void* d_out, int out_size, void* d_ws, size_t ws_size,
                              hipStream_t stream) {
  const float* x   = (const float*)d_in[0];
  const int* edge  = (const int*)d_in[1];
  const float* W1  = (const float*)d_in[3];
  const float* b1  = (const float*)d_in[4];
  const float* W2  = (const float*)d_in[5];
  const float* b2  = (const float*)d_in[6];
  const float* W3  = (const float*)d_in[7];
  const float* b3  = (const float*)d_in[8];
  const float* Wp1 = (const float*)d_in[9];
  const float* bp1 = (const float*)d_in[10];
  const float* Wp2 = (const float*)d_in[11];
  const float* bp2 = (const float*)d_in[12];
  float* out = (float*)d_out;

  const int n = in_sizes[0] / NDIM_IN;   // 100000
  const int E = in_sizes[1] / 2;         // 1600000
  const int* src = edge;
  const int* dst = edge + E;

  // workspace carve-out (256B aligned slices)
  char* ws = (char*)d_ws;
  size_t off = 0;
  auto carve = [&](size_t bytes) {
    char* p = ws + off;
    off = (off + bytes + 255) & ~(size_t)255;
    return p;
  };
  int*    histT = (int*)carve((size_t)NB * NC * 4);   // 800 KB
  int*    bsum  = (int*)carve(1024 * 4);
  int*    tmp   = (int*)carve((size_t)E * 4);         // 6.4 MB (packed)
  int*    col   = (int*)carve((size_t)E * 4);         // 6.4 MB
  int*    rp    = (int*)carve(((size_t)n + 1) * 4);
  float*  dinv  = (float*)carve((size_t)n * 4);
  __half* bufT  = (__half*)carve((size_t)n * HID * 2);
  float*  bufA  = (float*)carve((size_t)n * HID * 4);
  (void)ws_size; (void)n_in; (void)out_size;

  const int nbN = (n + 255) / 256;        // 391
  const int ntiles = (n + 15) >> 4;       // 6250
  const int nbM = 782;                    // mfma gemm blocks (2 tiles/wave)
  const int scan_len = NB * NC;           // 200192
  const int nbScan = (scan_len + 255) / 256;  // 782 == NB (alignment!)

  hist_k<<<NC, 256, 0, stream>>>(dst, histT, E);
  scan1<<<nbScan, 256, 0, stream>>>(histT, bsum, scan_len);
  scan2<<<1, 1024, 0, stream>>>(bsum, nbScan);
  scatter_k<<<NC, 256, 0, stream>>>(src, dst, histT, bsum, tmp, E);
  binsort_k<<<NB, 256, 0, stream>>>(tmp, bsum, col, rp, dinv, n, E);

  const int nbSp = ((n * 64) + 255) / 256;

  // layer 1: 128 -> 64
  gemm_mfma<128><<<nbM, 256, 0, stream>>>(x, W1, dinv, bufT, n, ntiles);
  spmm_relu<<<nbSp, 256, 0, stream>>>(rp, col, bufT, dinv, b1, bufA, n);
  // layer 2: 64 -> 64
  gemm_mfma<64><<<nbM, 256, 0, stream>>>(bufA, W2, dinv, bufT, n, ntiles);
  spmm_relu<<<nbSp, 256, 0, stream>>>(rp, col, bufT, dinv, b2, bufA, n);
  // layer 3: 64 -> 64
  gemm_mfma<64><<<nbM, 256, 0, stream>>>(bufA, W3, dinv, bufT, n, ntiles);
  spmm_relu<<<nbSp, 256, 0, stream>>>(rp, col, bufT, dinv, b3, bufA, n);
  // head
  mlp_head<<<nbN, 256, 0, stream>>>(bufA, Wp1, bp1, Wp2, bp2, out, n);
}